// Round 1
// baseline (70087.360 us; speedup 1.0000x reference)
//
#include <hip/hip_runtime.h>
#include <stdint.h>

// Problem dims
#define TT 2048
#define BB 32
#define II 256
#define HH 512
#define OO 1024
#define NWG 256
#define NL0 128   // WGs 0..127 = layer0, 128..255 = layer1

typedef __attribute__((ext_vector_type(8))) short short8;
typedef __attribute__((ext_vector_type(4))) float floatx4;

__device__ __forceinline__ unsigned short f2bf(float f) {
  union { float f; unsigned u; } v; v.f = f;
  unsigned r = v.u + 0x7FFFu + ((v.u >> 16) & 1u);  // RNE
  return (unsigned short)(r >> 16);
}
__device__ __forceinline__ float bf2f(unsigned short b) {
  union { float f; unsigned u; } v; v.u = ((unsigned)b) << 16; return v.f;
}
__device__ __forceinline__ float sigmf(float x) { return 1.0f / (1.0f + __expf(-x)); }

// ---------------- x fp32 -> bf16 convert ----------------
__global__ void k_convert_x(const float* __restrict__ x, ushort* __restrict__ xb, int n4) {
  int i = blockIdx.x * blockDim.x + threadIdx.x;
  int stride = gridDim.x * blockDim.x;
  const float4* xf = reinterpret_cast<const float4*>(x);
  ushort4* ob = reinterpret_cast<ushort4*>(xb);
  for (; i < n4; i += stride) {
    float4 f = xf[i];
    ushort4 o;
    o.x = f2bf(f.x); o.y = f2bf(f.y); o.z = f2bf(f.z); o.w = f2bf(f.w);
    ob[i] = o;
  }
}

// ---------------- init h buffers + barrier (every call: replay-deterministic) ----------------
__global__ void k_init(const float* __restrict__ h0in, ushort* __restrict__ h0b1,
                       ushort* __restrict__ h1b1, int* __restrict__ bar) {
  int i = threadIdx.x;
  for (int k = i; k < BB * HH; k += blockDim.x) {
    h0b1[k] = f2bf(h0in[k]);            // layer0 initial h  -> h0 buf[1] (read at phase 0)
    h1b1[k] = f2bf(h0in[BB * HH + k]);  // layer1 initial h  -> h1 buf[1] (read at phase 1)
  }
  for (int k = i; k < 1024; k += blockDim.x) bar[k] = 0;
}

// ---------------- persistent recurrence kernel ----------------
// WG g (layer L) owns hidden units [4g,4g+4): 16 gate columns n = gate*4 + u,
// gate in {i,f,g,o}. Weight B-fragments for mfma_f32_16x16x32_bf16 live in registers.
// Phase p: L0 computes h0[p] from x[p], h0[p-1]; L1 computes h1[p-1] from h0[p-1], h1[p-2].
// One tree barrier per phase.
__global__ __launch_bounds__(64, 1) void k_lstm(
    const ushort* __restrict__ xb,
    const float* __restrict__ w_ih0, const float* __restrict__ w_hh0,
    const float* __restrict__ b_ih0, const float* __restrict__ b_hh0,
    const float* __restrict__ w_ih1, const float* __restrict__ w_hh1,
    const float* __restrict__ b_ih1, const float* __restrict__ b_hh1,
    const float* __restrict__ c0in,
    ushort* __restrict__ h0b0, ushort* __restrict__ h0b1,
    ushort* __restrict__ h1b0, ushort* __restrict__ h1b1,
    int* __restrict__ bar)
{
  const int wg = blockIdx.x;
  const int lane = threadIdx.x;
  const bool isL0 = wg < NL0;
  const int g = isL0 ? wg : wg - NL0;
  const int col = lane & 15;       // output column n within the 16-wide tile
  const int krow = lane >> 4;      // k sub-block 0..3
  const int u = col & 3;           // hidden unit within slice
  const int gate = col >> 2;       // 0=i 1=f 2=g 3=o
  const int grow = gate * HH + 4 * g + u;  // row in [4H, K] weight matrices

  // --- pack weight B-fragments into registers (bf16) ---
  short8 wf[32];
#define LOADW(dst, base, rowlen, kbase) do {                                  \
    const float* _p = (base) + (size_t)grow * (rowlen) + (kbase) + krow * 8;  \
    short8 _r;                                                                \
    _Pragma("unroll")                                                         \
    for (int _j = 0; _j < 8; _j++) _r[_j] = (short)f2bf(_p[_j]);              \
    (dst) = _r; } while (0)

  if (isL0) {
#pragma unroll
    for (int kk = 0; kk < 8; kk++)  LOADW(wf[kk],      w_ih0, II, kk * 32);   // x proj, K=256
#pragma unroll
    for (int kk = 0; kk < 16; kk++) LOADW(wf[8 + kk],  w_hh0, HH, kk * 32);   // h proj, K=512
  } else {
#pragma unroll
    for (int kk = 0; kk < 16; kk++) LOADW(wf[kk],      w_ih1, HH, kk * 32);   // h0 proj
#pragma unroll
    for (int kk = 0; kk < 16; kk++) LOADW(wf[16 + kk], w_hh1, HH, kk * 32);   // h1 proj
  }
  const float bias = isL0 ? (b_ih0[grow] + b_hh0[grow]) : (b_ih1[grow] + b_hh1[grow]);

  // --- c state in fp32 registers (valid in gate==0 lanes) ---
  float cst[2][4];
  {
    const float* cbase = c0in + (isL0 ? 0 : 1) * BB * HH;
#pragma unroll
    for (int tt = 0; tt < 2; tt++)
#pragma unroll
      for (int r = 0; r < 4; r++) {
        int b = tt * 16 + krow * 4 + r;
        cst[tt][r] = cbase[b * HH + 4 * g + u];
      }
  }

  ushort* h0w[2] = { h0b0, h0b1 };
  ushort* h1w[2] = { h1b0, h1b1 };
  int* gcnt = bar + (wg & 15) * 32;  // 16 groups of 16 WGs
  int* root = bar + 512;
  int* gen  = bar + 544;

  const int P = TT + 1;
  for (int p = 0; p < P; ++p) {
    const bool active = isL0 ? (p < TT) : (p >= 1);
    if (active) {
      floatx4 acc[2];
      acc[0] = (floatx4){ bias, bias, bias, bias };
      acc[1] = acc[0];
      if (isL0) {
        const ushort* xr = xb + (size_t)p * BB * II;
        const ushort* hr = h0w[(p + 1) & 1];  // h0[p-1]
#pragma unroll
        for (int tt = 0; tt < 2; tt++) {
          const int b = tt * 16 + col;
#pragma unroll
          for (int kk = 0; kk < 8; kk++) {
            short8 a = *reinterpret_cast<const short8*>(xr + b * II + kk * 32 + krow * 8);
            acc[tt] = __builtin_amdgcn_mfma_f32_16x16x32_bf16(a, wf[kk], acc[tt], 0, 0, 0);
          }
#pragma unroll
          for (int kk = 0; kk < 16; kk++) {
            short8 a = *reinterpret_cast<const short8*>(hr + b * HH + kk * 32 + krow * 8);
            acc[tt] = __builtin_amdgcn_mfma_f32_16x16x32_bf16(a, wf[8 + kk], acc[tt], 0, 0, 0);
          }
        }
      } else {
        const int t = p - 1;
        const ushort* h0r = h0w[t & 1];        // h0[t]
        const ushort* h1r = h1w[(t + 1) & 1];  // h1[t-1]
#pragma unroll
        for (int tt = 0; tt < 2; tt++) {
          const int b = tt * 16 + col;
#pragma unroll
          for (int kk = 0; kk < 16; kk++) {
            short8 a = *reinterpret_cast<const short8*>(h0r + b * HH + kk * 32 + krow * 8);
            acc[tt] = __builtin_amdgcn_mfma_f32_16x16x32_bf16(a, wf[kk], acc[tt], 0, 0, 0);
          }
#pragma unroll
          for (int kk = 0; kk < 16; kk++) {
            short8 a = *reinterpret_cast<const short8*>(h1r + b * HH + kk * 32 + krow * 8);
            acc[tt] = __builtin_amdgcn_mfma_f32_16x16x32_bf16(a, wf[16 + kk], acc[tt], 0, 0, 0);
          }
        }
      }
      // gate nonlinearities + state update; D layout: col=lane&15, row=(lane>>4)*4+reg
      ushort* hw = isL0 ? h0w[p & 1] : h1w[(p - 1) & 1];
#pragma unroll
      for (int tt = 0; tt < 2; tt++) {
#pragma unroll
        for (int r = 0; r < 4; r++) {
          float val = acc[tt][r];
          int base = (lane & 48) | u;
          float iv = __shfl(val, base);
          float fv = __shfl(val, base | 4);
          float gv = __shfl(val, base | 8);
          float ov = __shfl(val, base | 12);
          if (gate == 0) {
            float cn = sigmf(fv) * cst[tt][r] + sigmf(iv) * tanhf(gv);
            cst[tt][r] = cn;
            float hn = sigmf(ov) * tanhf(cn);
            int b = tt * 16 + krow * 4 + r;
            hw[b * HH + 4 * g + u] = f2bf(hn);
          }
        }
      }
    }
    // ---- grid barrier (two-level tree, device-scope) ----
    if (p != P - 1) {
      __threadfence();  // release h writes
      if (lane == 0) {
        const int target = p + 1;
        int prev = __hip_atomic_fetch_add(gcnt, 1, __ATOMIC_RELAXED, __HIP_MEMORY_SCOPE_AGENT);
        if (prev == 15) {
          int p2 = __hip_atomic_fetch_add(root, 1, __ATOMIC_RELAXED, __HIP_MEMORY_SCOPE_AGENT);
          if (p2 == 15) {
#pragma unroll
            for (int q = 0; q < 16; q++)
              __hip_atomic_store(bar + q * 32, 0, __ATOMIC_RELAXED, __HIP_MEMORY_SCOPE_AGENT);
            __hip_atomic_store(root, 0, __ATOMIC_RELAXED, __HIP_MEMORY_SCOPE_AGENT);
            __hip_atomic_fetch_add(gen, 1, __ATOMIC_RELEASE, __HIP_MEMORY_SCOPE_AGENT);
          } else {
            while (__hip_atomic_load(gen, __ATOMIC_ACQUIRE, __HIP_MEMORY_SCOPE_AGENT) < target)
              __builtin_amdgcn_s_sleep(2);
          }
        } else {
          while (__hip_atomic_load(gen, __ATOMIC_ACQUIRE, __HIP_MEMORY_SCOPE_AGENT) < target)
            __builtin_amdgcn_s_sleep(2);
        }
      }
      __threadfence();  // acquire side: invalidate stale h lines
    }
  }
}

// ---------------- FC + log_softmax ----------------
__global__ __launch_bounds__(256) void k_fc(const ushort* __restrict__ h1,
                                            const float* __restrict__ fcw,
                                            const float* __restrict__ fcb,
                                            float* __restrict__ out) {
  __shared__ float hsh[HH];
  __shared__ float red[256];
  const int b = blockIdx.x, tid = threadIdx.x;
  for (int k = tid; k < HH; k += 256) hsh[k] = bf2f(h1[b * HH + k]);
  __syncthreads();
  float lg[4];
#pragma unroll
  for (int q = 0; q < 4; q++) {
    int o = q * 256 + tid;
    float acc = fcb[o];
    const float* wr = fcw + (size_t)o * HH;
#pragma unroll 4
    for (int k = 0; k < HH; k += 4) {
      float4 w4 = *reinterpret_cast<const float4*>(wr + k);
      acc += hsh[k] * w4.x + hsh[k + 1] * w4.y + hsh[k + 2] * w4.z + hsh[k + 3] * w4.w;
    }
    lg[q] = acc;
  }
  float m = fmaxf(fmaxf(lg[0], lg[1]), fmaxf(lg[2], lg[3]));
  red[tid] = m; __syncthreads();
  for (int s = 128; s > 0; s >>= 1) { if (tid < s) red[tid] = fmaxf(red[tid], red[tid + s]); __syncthreads(); }
  m = red[0]; __syncthreads();
  float se = 0.f;
#pragma unroll
  for (int q = 0; q < 4; q++) se += __expf(lg[q] - m);
  red[tid] = se; __syncthreads();
  for (int s = 128; s > 0; s >>= 1) { if (tid < s) red[tid] += red[tid + s]; __syncthreads(); }
  float lse = m + logf(red[0]);
#pragma unroll
  for (int q = 0; q < 4; q++) out[b * OO + q * 256 + tid] = lg[q] - lse;
}

extern "C" void kernel_launch(void* const* d_in, const int* in_sizes, int n_in,
                              void* d_out, int out_size, void* d_ws, size_t ws_size,
                              hipStream_t stream) {
  const float* x     = (const float*)d_in[0];
  const float* h0    = (const float*)d_in[1];
  const float* c0    = (const float*)d_in[2];
  const float* w_ih0 = (const float*)d_in[3];
  const float* w_hh0 = (const float*)d_in[4];
  const float* b_ih0 = (const float*)d_in[5];
  const float* b_hh0 = (const float*)d_in[6];
  const float* w_ih1 = (const float*)d_in[7];
  const float* w_hh1 = (const float*)d_in[8];
  const float* b_ih1 = (const float*)d_in[9];
  const float* b_hh1 = (const float*)d_in[10];
  const float* fcw   = (const float*)d_in[11];
  const float* fcb   = (const float*)d_in[12];
  float* out = (float*)d_out;

  char* ws = (char*)d_ws;
  size_t off = 0;
  ushort* xb = (ushort*)(ws + off); off += (size_t)TT * BB * II * 2;   // 33.5 MB
  ushort* h0b0 = (ushort*)(ws + off); off += BB * HH * 2;
  ushort* h0b1 = (ushort*)(ws + off); off += BB * HH * 2;
  ushort* h1b0 = (ushort*)(ws + off); off += BB * HH * 2;
  ushort* h1b1 = (ushort*)(ws + off); off += BB * HH * 2;
  int* bar = (int*)(ws + off); off += 1024 * sizeof(int);

  k_convert_x<<<2048, 256, 0, stream>>>(x, xb, TT * BB * II / 4);
  k_init<<<1, 256, 0, stream>>>(h0, h0b1, h1b1, bar);
  k_lstm<<<NWG, 64, 0, stream>>>(xb, w_ih0, w_hh0, b_ih0, b_hh0,
                                 w_ih1, w_hh1, b_ih1, b_hh1, c0,
                                 h0b0, h0b1, h1b0, h1b1, bar);
  // h1[2047] lives in h1 buf[2047&1] = h1b1
  k_fc<<<BB, 256, 0, stream>>>(h1b1, fcw, fcb, out);
}

// Round 2
// 37032.834 us; speedup vs baseline: 1.8926x; 1.8926x over previous
//
#include <hip/hip_runtime.h>
#include <stdint.h>

// Problem dims
#define TT 2048
#define BB 32
#define II 256
#define HH 512
#define OO 1024
#define NWGL 64    // WGs per layer (each owns 8 hidden units = 32 gate columns)
#define NWG 128

typedef __attribute__((ext_vector_type(8))) short short8;
typedef __attribute__((ext_vector_type(4))) float floatx4;

__device__ __forceinline__ unsigned short f2bf(float f) {
  union { float f; unsigned u; } v; v.f = f;
  unsigned r = v.u + 0x7FFFu + ((v.u >> 16) & 1u);  // RNE
  return (unsigned short)(r >> 16);
}
__device__ __forceinline__ float bf2f(unsigned short b) {
  union { float f; unsigned u; } v; v.u = ((unsigned)b) << 16; return v.f;
}
__device__ __forceinline__ float sigmf(float x) { return 1.0f / (1.0f + __expf(-x)); }
__device__ __forceinline__ float tanhfast(float x) {
  float xc = fminf(fmaxf(x, -15.f), 15.f);
  float e = __expf(2.f * xc);
  return (e - 1.f) / (e + 1.f);
}
// 2-byte store that bypasses L1/L2 straight to L3 (agent-coherent point).
__device__ __forceinline__ void store_short_sc1(ushort* p, unsigned v) {
  asm volatile("global_store_short %0, %1, off sc0 sc1" :: "v"(p), "v"(v) : "memory");
}

// ---------------- x fp32 -> bf16 convert ----------------
__global__ void k_convert_x(const float* __restrict__ x, ushort* __restrict__ xb, int n4) {
  int i = blockIdx.x * blockDim.x + threadIdx.x;
  int stride = gridDim.x * blockDim.x;
  const float4* xf = reinterpret_cast<const float4*>(x);
  ushort4* ob = reinterpret_cast<ushort4*>(xb);
  for (; i < n4; i += stride) {
    float4 f = xf[i];
    ushort4 o;
    o.x = f2bf(f.x); o.y = f2bf(f.y); o.z = f2bf(f.z); o.w = f2bf(f.w);
    ob[i] = o;
  }
}

// ---------------- init h buffers + barrier (every call: replay-deterministic) ----------------
__global__ void k_init(const float* __restrict__ h0in, ushort* __restrict__ h0b1,
                       ushort* __restrict__ h1b1, int* __restrict__ bar) {
  int i = threadIdx.x;
  for (int k = i; k < BB * HH; k += blockDim.x) {
    h0b1[k] = f2bf(h0in[k]);            // layer0 initial h -> h0 buf[1]
    h1b1[k] = f2bf(h0in[BB * HH + k]);  // layer1 initial h -> h1 buf[1]
  }
  for (int k = i; k < 1024; k += blockDim.x) bar[k] = 0;
}

// ---------------- persistent recurrence kernel ----------------
// 128 WGs x 1 wave. WG g of layer L owns hidden units [8g, 8g+8): two 16-wide MFMA
// column tiles (tau=0: units 8g..8g+3, tau=1: 8g+4..8g+7), gate order i,f,g,o per tile.
// Weights live in registers as MFMA B-fragments (<=256 VGPR).
// Phase p: L0 computes h0[p]; L1 computes h1[p-1]. One grid barrier per phase.
// Sync design: h stores are sc0sc1 (straight to L3); barrier counters are MONOTONIC
// relaxed agent atomics (no cache ops per poll); one acquire fence per phase after
// barrier exit makes normal (compiler-pipelined) h/x loads refetch from L3.
__global__ __launch_bounds__(64, 1) void k_lstm(
    const ushort* __restrict__ xb,
    const float* __restrict__ w_ih0, const float* __restrict__ w_hh0,
    const float* __restrict__ b_ih0, const float* __restrict__ b_hh0,
    const float* __restrict__ w_ih1, const float* __restrict__ w_hh1,
    const float* __restrict__ b_ih1, const float* __restrict__ b_hh1,
    const float* __restrict__ c0in,
    ushort* __restrict__ h0b0, ushort* __restrict__ h0b1,
    ushort* __restrict__ h1b0, ushort* __restrict__ h1b1,
    int* __restrict__ bar)
{
  const int wg = blockIdx.x;
  const int lane = threadIdx.x;
  const bool isL0 = wg < NWGL;
  const int g = isL0 ? wg : wg - NWGL;
  const int col = lane & 15;       // column within a 16-wide tile
  const int krow = lane >> 4;      // k sub-block 0..3
  const int u = col & 3;           // hidden unit within a tile's 4-unit slice
  const int gate = col >> 2;       // 0=i 1=f 2=g 3=o

  // --- pack weight B-fragments into registers (bf16) ---
  short8 wf[2][32];
#define LOADW(dst, base, rowlen, kbase, tau) do {                             \
    const int _grow = gate * HH + g * 8 + (tau) * 4 + u;                      \
    const float* _p = (base) + (size_t)_grow * (rowlen) + (kbase) + krow * 8; \
    short8 _r;                                                                \
    _Pragma("unroll")                                                         \
    for (int _j = 0; _j < 8; _j++) _r[_j] = (short)f2bf(_p[_j]);              \
    (dst) = _r; } while (0)

  if (isL0) {
#pragma unroll
    for (int tau = 0; tau < 2; tau++) {
#pragma unroll
      for (int kk = 0; kk < 8; kk++)  LOADW(wf[tau][kk],      w_ih0, II, kk * 32, tau);
#pragma unroll
      for (int kk = 0; kk < 16; kk++) LOADW(wf[tau][8 + kk],  w_hh0, HH, kk * 32, tau);
    }
  } else {
#pragma unroll
    for (int tau = 0; tau < 2; tau++) {
#pragma unroll
      for (int kk = 0; kk < 16; kk++) LOADW(wf[tau][kk],      w_ih1, HH, kk * 32, tau);
#pragma unroll
      for (int kk = 0; kk < 16; kk++) LOADW(wf[tau][16 + kk], w_hh1, HH, kk * 32, tau);
    }
  }
  float bias[2];
#pragma unroll
  for (int tau = 0; tau < 2; tau++) {
    const int grow = gate * HH + g * 8 + tau * 4 + u;
    bias[tau] = isL0 ? (b_ih0[grow] + b_hh0[grow]) : (b_ih1[grow] + b_hh1[grow]);
  }

  // --- c state in fp32 registers (valid in gate==0 lanes) ---
  float cst[2][2][4];
  {
    const float* cbase = c0in + (isL0 ? 0 : 1) * BB * HH;
#pragma unroll
    for (int tau = 0; tau < 2; tau++)
#pragma unroll
      for (int tt = 0; tt < 2; tt++)
#pragma unroll
        for (int r = 0; r < 4; r++) {
          int b = tt * 16 + krow * 4 + r;
          cst[tau][tt][r] = cbase[b * HH + g * 8 + tau * 4 + u];
        }
  }

  ushort* h0bufs[2] = { h0b0, h0b1 };
  ushort* h1bufs[2] = { h1b0, h1b1 };
  int* gcnt = bar + (wg >> 4) * 32;  // 8 groups of 16 WGs, 128B apart
  int* root = bar + 512;
  int* gen  = bar + 544;

  const int P = TT + 1;
  for (int p = 0; p < P; ++p) {
    const bool active = isL0 ? (p < TT) : (p >= 1);
    if (active) {
      floatx4 acc[2][2];  // [tile tau][batch tile tt]
#pragma unroll
      for (int tau = 0; tau < 2; tau++) {
        floatx4 bi = (floatx4){ bias[tau], bias[tau], bias[tau], bias[tau] };
        acc[tau][0] = bi; acc[tau][1] = bi;
      }
      if (isL0) {
        const ushort* xr = xb + (size_t)p * BB * II;
        const ushort* hr = h0bufs[(p + 1) & 1];  // h0[p-1]
#pragma unroll
        for (int tt = 0; tt < 2; tt++) {
          const int b = tt * 16 + col;
#pragma unroll
          for (int kk = 0; kk < 8; kk++) {
            short8 a = *reinterpret_cast<const short8*>(xr + b * II + kk * 32 + krow * 8);
            acc[0][tt] = __builtin_amdgcn_mfma_f32_16x16x32_bf16(a, wf[0][kk], acc[0][tt], 0, 0, 0);
            acc[1][tt] = __builtin_amdgcn_mfma_f32_16x16x32_bf16(a, wf[1][kk], acc[1][tt], 0, 0, 0);
          }
#pragma unroll
          for (int kk = 0; kk < 16; kk++) {
            short8 a = *reinterpret_cast<const short8*>(hr + b * HH + kk * 32 + krow * 8);
            acc[0][tt] = __builtin_amdgcn_mfma_f32_16x16x32_bf16(a, wf[0][8 + kk], acc[0][tt], 0, 0, 0);
            acc[1][tt] = __builtin_amdgcn_mfma_f32_16x16x32_bf16(a, wf[1][8 + kk], acc[1][tt], 0, 0, 0);
          }
        }
      } else {
        const int t = p - 1;
        const ushort* h0r = h0bufs[t & 1];        // h0[t]
        const ushort* h1r = h1bufs[(t + 1) & 1];  // h1[t-1]
#pragma unroll
        for (int tt = 0; tt < 2; tt++) {
          const int b = tt * 16 + col;
#pragma unroll
          for (int kk = 0; kk < 16; kk++) {
            short8 a = *reinterpret_cast<const short8*>(h0r + b * HH + kk * 32 + krow * 8);
            acc[0][tt] = __builtin_amdgcn_mfma_f32_16x16x32_bf16(a, wf[0][kk], acc[0][tt], 0, 0, 0);
            acc[1][tt] = __builtin_amdgcn_mfma_f32_16x16x32_bf16(a, wf[1][kk], acc[1][tt], 0, 0, 0);
          }
#pragma unroll
          for (int kk = 0; kk < 16; kk++) {
            short8 a = *reinterpret_cast<const short8*>(h1r + b * HH + kk * 32 + krow * 8);
            acc[0][tt] = __builtin_amdgcn_mfma_f32_16x16x32_bf16(a, wf[0][16 + kk], acc[0][tt], 0, 0, 0);
            acc[1][tt] = __builtin_amdgcn_mfma_f32_16x16x32_bf16(a, wf[1][16 + kk], acc[1][tt], 0, 0, 0);
          }
        }
      }
      // gate nonlinearities + state update; D layout: col=lane&15, row=(lane>>4)*4+reg
      ushort* hw = isL0 ? h0bufs[p & 1] : h1bufs[(p - 1) & 1];
#pragma unroll
      for (int tau = 0; tau < 2; tau++) {
#pragma unroll
        for (int tt = 0; tt < 2; tt++) {
#pragma unroll
          for (int r = 0; r < 4; r++) {
            float val = acc[tau][tt][r];
            int base = (lane & 48) | u;
            float iv = __shfl(val, base);
            float fv = __shfl(val, base | 4);
            float gv = __shfl(val, base | 8);
            float ov = __shfl(val, base | 12);
            if (gate == 0) {
              float cn = sigmf(fv) * cst[tau][tt][r] + sigmf(iv) * tanhfast(gv);
              cst[tau][tt][r] = cn;
              float hn = sigmf(ov) * tanhfast(cn);
              int b = tt * 16 + krow * 4 + r;
              store_short_sc1(hw + b * HH + g * 8 + tau * 4 + u, (unsigned)f2bf(hn));
            }
          }
        }
      }
    }
    // ---- grid barrier: monotonic counters, relaxed atomics only ----
    if (p != P - 1) {
      // release: sc1 h-stores are visible at L3 once vmcnt drains; nothing dirty in L2.
      asm volatile("s_waitcnt vmcnt(0)" ::: "memory");
      if (lane == 0) {
        const int target = p + 1;
        int prev = __hip_atomic_fetch_add(gcnt, 1, __ATOMIC_RELAXED, __HIP_MEMORY_SCOPE_AGENT);
        if (prev == 16 * target - 1) {          // last in group
          int p2 = __hip_atomic_fetch_add(root, 1, __ATOMIC_RELAXED, __HIP_MEMORY_SCOPE_AGENT);
          if (p2 == 8 * target - 1) {           // last overall
            __hip_atomic_store(gen, target, __ATOMIC_RELAXED, __HIP_MEMORY_SCOPE_AGENT);
          } else {
            while (__hip_atomic_load(gen, __ATOMIC_RELAXED, __HIP_MEMORY_SCOPE_AGENT) < target)
              __builtin_amdgcn_s_sleep(2);
          }
        } else {
          while (__hip_atomic_load(gen, __ATOMIC_RELAXED, __HIP_MEMORY_SCOPE_AGENT) < target)
            __builtin_amdgcn_s_sleep(2);
        }
      }
      // acquire: one L1/L2 invalidate per phase so normal loads see fresh L3 data.
      __builtin_amdgcn_fence(__ATOMIC_ACQUIRE, "agent");
    }
  }
}

// ---------------- FC + log_softmax ----------------
__global__ __launch_bounds__(256) void k_fc(const ushort* __restrict__ h1,
                                            const float* __restrict__ fcw,
                                            const float* __restrict__ fcb,
                                            float* __restrict__ out) {
  __shared__ float hsh[HH];
  __shared__ float red[256];
  const int b = blockIdx.x, tid = threadIdx.x;
  for (int k = tid; k < HH; k += 256) hsh[k] = bf2f(h1[b * HH + k]);
  __syncthreads();
  float lg[4];
#pragma unroll
  for (int q = 0; q < 4; q++) {
    int o = q * 256 + tid;
    float acc = fcb[o];
    const float* wr = fcw + (size_t)o * HH;
#pragma unroll 4
    for (int k = 0; k < HH; k += 4) {
      float4 w4 = *reinterpret_cast<const float4*>(wr + k);
      acc += hsh[k] * w4.x + hsh[k + 1] * w4.y + hsh[k + 2] * w4.z + hsh[k + 3] * w4.w;
    }
    lg[q] = acc;
  }
  float m = fmaxf(fmaxf(lg[0], lg[1]), fmaxf(lg[2], lg[3]));
  red[tid] = m; __syncthreads();
  for (int s = 128; s > 0; s >>= 1) { if (tid < s) red[tid] = fmaxf(red[tid], red[tid + s]); __syncthreads(); }
  m = red[0]; __syncthreads();
  float se = 0.f;
#pragma unroll
  for (int q = 0; q < 4; q++) se += __expf(lg[q] - m);
  red[tid] = se; __syncthreads();
  for (int s = 128; s > 0; s >>= 1) { if (tid < s) red[tid] += red[tid + s]; __syncthreads(); }
  float lse = m + logf(red[0]);
#pragma unroll
  for (int q = 0; q < 4; q++) out[b * OO + q * 256 + tid] = lg[q] - lse;
}

extern "C" void kernel_launch(void* const* d_in, const int* in_sizes, int n_in,
                              void* d_out, int out_size, void* d_ws, size_t ws_size,
                              hipStream_t stream) {
  const float* x     = (const float*)d_in[0];
  const float* h0    = (const float*)d_in[1];
  const float* c0    = (const float*)d_in[2];
  const float* w_ih0 = (const float*)d_in[3];
  const float* w_hh0 = (const float*)d_in[4];
  const float* b_ih0 = (const float*)d_in[5];
  const float* b_hh0 = (const float*)d_in[6];
  const float* w_ih1 = (const float*)d_in[7];
  const float* w_hh1 = (const float*)d_in[8];
  const float* b_ih1 = (const float*)d_in[9];
  const float* b_hh1 = (const float*)d_in[10];
  const float* fcw   = (const float*)d_in[11];
  const float* fcb   = (const float*)d_in[12];
  float* out = (float*)d_out;

  char* ws = (char*)d_ws;
  size_t off = 0;
  ushort* xb = (ushort*)(ws + off); off += (size_t)TT * BB * II * 2;   // 33.5 MB
  ushort* h0b0 = (ushort*)(ws + off); off += BB * HH * 2;
  ushort* h0b1 = (ushort*)(ws + off); off += BB * HH * 2;
  ushort* h1b0 = (ushort*)(ws + off); off += BB * HH * 2;
  ushort* h1b1 = (ushort*)(ws + off); off += BB * HH * 2;
  int* bar = (int*)(ws + off); off += 1024 * sizeof(int);

  k_convert_x<<<2048, 256, 0, stream>>>(x, xb, TT * BB * II / 4);
  k_init<<<1, 256, 0, stream>>>(h0, h0b1, h1b1, bar);
  k_lstm<<<NWG, 64, 0, stream>>>(xb, w_ih0, w_hh0, b_ih0, b_hh0,
                                 w_ih1, w_hh1, b_ih1, b_hh1, c0,
                                 h0b0, h0b1, h1b0, h1b1, bar);
  // h1[2047] lives in h1 buf[2047&1] = h1b1
  k_fc<<<BB, 256, 0, stream>>>(h1b1, fcw, fcb, out);
}

// Round 4
// 17625.479 us; speedup vs baseline: 3.9765x; 2.1011x over previous
//
#include <hip/hip_runtime.h>
#include <stdint.h>

// Problem dims
#define TT 2048
#define BB 32
#define II 256
#define HH 512
#define OO 1024
#define NWGL 64    // WGs per layer (each owns 8 hidden units = 32 gate columns)
#define NWG 128

typedef __attribute__((ext_vector_type(8))) short short8;
typedef __attribute__((ext_vector_type(4))) float floatx4;

__device__ __forceinline__ unsigned short f2bf(float f) {
  union { float f; unsigned u; } v; v.f = f;
  unsigned r = v.u + 0x7FFFu + ((v.u >> 16) & 1u);  // RNE
  return (unsigned short)(r >> 16);
}
__device__ __forceinline__ float bf2f(unsigned short b) {
  union { float f; unsigned u; } v; v.u = ((unsigned)b) << 16; return v.f;
}
__device__ __forceinline__ float sigmf(float x) { return 1.0f / (1.0f + __expf(-x)); }
__device__ __forceinline__ float tanhfast(float x) {
  float xc = fminf(fmaxf(x, -15.f), 15.f);
  float e = __expf(2.f * xc);
  return (e - 1.f) / (e + 1.f);
}

// Coherent (L3-direct) 16B load via 64-bit VGPR address: d <- [va + IMM].
#define LD1(d, va, IMM)                                                     \
  asm volatile("global_load_dwordx4 %0, %1, off offset:" IMM " sc0 sc1"     \
               : "=v"(d) : "v"(va) : "memory")

#define ISSUE8(dst, va) do {                                                \
    LD1(dst[0], va, "0");   LD1(dst[1], va, "64");                          \
    LD1(dst[2], va, "128"); LD1(dst[3], va, "192");                         \
    LD1(dst[4], va, "256"); LD1(dst[5], va, "320");                         \
    LD1(dst[6], va, "384"); LD1(dst[7], va, "448"); } while (0)

// Wait until <=N vector-mem ops outstanding; fence the scheduler so MFMAs
// consuming asm-loaded regs can't hoist above (rule #18).
#define WAITV(N) do {                                                       \
    asm volatile("s_waitcnt vmcnt(" #N ")" ::: "memory");                   \
    __builtin_amdgcn_sched_barrier(0); } while (0)

#define MF8(tt_, src, wbase) do {                                           \
    _Pragma("unroll")                                                       \
    for (int j = 0; j < 8; j++) {                                           \
      acc[0][tt_] = __builtin_amdgcn_mfma_f32_16x16x32_bf16(src[j], wf[0][(wbase) + j], acc[0][tt_], 0, 0, 0); \
      acc[1][tt_] = __builtin_amdgcn_mfma_f32_16x16x32_bf16(src[j], wf[1][(wbase) + j], acc[1][tt_], 0, 0, 0); \
    } } while (0)

// ---------------- x fp32 -> bf16 convert ----------------
__global__ void k_convert_x(const float* __restrict__ x, ushort* __restrict__ xb, int n4) {
  int i = blockIdx.x * blockDim.x + threadIdx.x;
  int stride = gridDim.x * blockDim.x;
  const float4* xf = reinterpret_cast<const float4*>(x);
  ushort4* ob = reinterpret_cast<ushort4*>(xb);
  for (; i < n4; i += stride) {
    float4 f = xf[i];
    ushort4 o;
    o.x = f2bf(f.x); o.y = f2bf(f.y); o.z = f2bf(f.z); o.w = f2bf(f.w);
    ob[i] = o;
  }
}

// ---------------- init h buffers + barrier ----------------
__global__ void k_init(const float* __restrict__ h0in, ushort* __restrict__ h0b1,
                       ushort* __restrict__ h1b1, int* __restrict__ bar) {
  int i = threadIdx.x;
  for (int k = i; k < BB * HH; k += blockDim.x) {
    h0b1[k] = f2bf(h0in[k]);
    h1b1[k] = f2bf(h0in[BB * HH + k]);
  }
  for (int k = i; k < 1024; k += blockDim.x) bar[k] = 0;
}

// ---------------- persistent recurrence kernel ----------------
// 128 WGs x 1 wave. No cache-wide ops in the loop: h moves through L3 via
// sc0sc1 loads/stores; x + weights stay in normal caches (never invalidated).
// h loads are hand-pipelined (8-load chunks, 16 in flight, counted vmcnt).
__global__ __launch_bounds__(64, 1) void k_lstm(
    const ushort* __restrict__ xb,
    const float* __restrict__ w_ih0, const float* __restrict__ w_hh0,
    const float* __restrict__ b_ih0, const float* __restrict__ b_hh0,
    const float* __restrict__ w_ih1, const float* __restrict__ w_hh1,
    const float* __restrict__ b_ih1, const float* __restrict__ b_hh1,
    const float* __restrict__ c0in,
    ushort* __restrict__ h0b0, ushort* __restrict__ h0b1,
    ushort* __restrict__ h1b0, ushort* __restrict__ h1b1,
    int* __restrict__ bar)
{
  __shared__ ushort sh[BB][8];  // 512B store-coalescing tile
  const int wg = blockIdx.x;
  const int lane = threadIdx.x;
  const bool isL0 = wg < NWGL;
  const int g = isL0 ? wg : wg - NWGL;
  const int col = lane & 15;
  const int krow = lane >> 4;
  const int u = col & 3;
  const int gate = col >> 2;  // 0=i 1=f 2=g 3=o

  // --- pack weight B-fragments into registers (bf16) ---
  short8 wf[2][32];
#define LOADW(dst, base, rowlen, kbase, tau) do {                             \
    const int _grow = gate * HH + g * 8 + (tau) * 4 + u;                      \
    const float* _p = (base) + (size_t)_grow * (rowlen) + (kbase) + krow * 8; \
    short8 _r;                                                                \
    _Pragma("unroll")                                                         \
    for (int _j = 0; _j < 8; _j++) _r[_j] = (short)f2bf(_p[_j]);              \
    (dst) = _r; } while (0)

  if (isL0) {
#pragma unroll
    for (int tau = 0; tau < 2; tau++) {
#pragma unroll
      for (int kk = 0; kk < 8; kk++)  LOADW(wf[tau][kk],      w_ih0, II, kk * 32, tau);
#pragma unroll
      for (int kk = 0; kk < 16; kk++) LOADW(wf[tau][8 + kk],  w_hh0, HH, kk * 32, tau);
    }
  } else {
#pragma unroll
    for (int tau = 0; tau < 2; tau++) {
#pragma unroll
      for (int kk = 0; kk < 16; kk++) LOADW(wf[tau][kk],      w_ih1, HH, kk * 32, tau);
#pragma unroll
      for (int kk = 0; kk < 16; kk++) LOADW(wf[tau][16 + kk], w_hh1, HH, kk * 32, tau);
    }
  }
  float bias[2];
#pragma unroll
  for (int tau = 0; tau < 2; tau++) {
    const int grow = gate * HH + g * 8 + tau * 4 + u;
    bias[tau] = isL0 ? (b_ih0[grow] + b_hh0[grow]) : (b_ih1[grow] + b_hh1[grow]);
  }

  // --- c state in fp32 registers (used in gate==0 lanes) ---
  float cst[2][2][4];
  {
    const float* cbase = c0in + (isL0 ? 0 : 1) * BB * HH;
#pragma unroll
    for (int tau = 0; tau < 2; tau++)
#pragma unroll
      for (int tt = 0; tt < 2; tt++)
#pragma unroll
        for (int r = 0; r < 4; r++) {
          int b = tt * 16 + krow * 4 + r;
          cst[tau][tt][r] = cbase[b * HH + g * 8 + tau * 4 + u];
        }
  }

  ushort* h0bufs[2] = { h0b0, h0b1 };
  ushort* h1bufs[2] = { h1b0, h1b1 };
  int* gcnt = bar + (wg >> 4) * 32;
  int* root = bar + 512;
  int* gen  = bar + 544;

  // per-lane byte offsets into a [32][512] bf16 h tile
  const int vo00 = col * 1024 + krow * 16;  // tt=0 base; tt=1 = +16384
  const unsigned long long stoff = (unsigned long long)(lane * 1024 + g * 16);

  const int P = TT + 1;
  for (int p = 0; p < P; ++p) {
    const bool active = isL0 ? (p < TT) : (p >= 1);
    if (active) {
      floatx4 acc[2][2];
#pragma unroll
      for (int tau = 0; tau < 2; tau++) {
        floatx4 bi = (floatx4){ bias[tau], bias[tau], bias[tau], bias[tau] };
        acc[tau][0] = bi; acc[tau][1] = bi;
      }
      short8 wa[8], wb[8];
      if (isL0) {
        // x part: normal cached loads (x is read-only; L2-resident per XCD)
        const ushort* xr = xb + (size_t)p * BB * II;
#pragma unroll
        for (int tt = 0; tt < 2; tt++) {
          const int b = tt * 16 + col;
#pragma unroll
          for (int kk = 0; kk < 8; kk++) {
            short8 a = *reinterpret_cast<const short8*>(xr + b * II + kk * 32 + krow * 8);
            acc[0][tt] = __builtin_amdgcn_mfma_f32_16x16x32_bf16(a, wf[0][kk], acc[0][tt], 0, 0, 0);
            acc[1][tt] = __builtin_amdgcn_mfma_f32_16x16x32_bf16(a, wf[1][kk], acc[1][tt], 0, 0, 0);
          }
        }
        // h part: coherent pipelined loads, 4 chunks of 8
        const unsigned long long ha = (unsigned long long)h0bufs[(p + 1) & 1] + vo00;
        ISSUE8(wa, ha);
        ISSUE8(wb, ha + 512);
        WAITV(8);  MF8(0, wa, 8);
        ISSUE8(wa, ha + 16384);
        WAITV(8);  MF8(0, wb, 16);
        ISSUE8(wb, ha + 16896);
        WAITV(8);  MF8(1, wa, 8);
        WAITV(0);  MF8(1, wb, 16);
      } else {
        const int t = p - 1;
        const unsigned long long a0 = (unsigned long long)h0bufs[t & 1] + vo00;
        const unsigned long long a1 = (unsigned long long)h1bufs[(t + 1) & 1] + vo00;
        // 8 chunks of 8 coherent loads, depth-16 pipeline
        ISSUE8(wa, a0);
        ISSUE8(wb, a0 + 512);
        WAITV(8);  MF8(0, wa, 0);
        ISSUE8(wa, a0 + 16384);
        WAITV(8);  MF8(0, wb, 8);
        ISSUE8(wb, a0 + 16896);
        WAITV(8);  MF8(1, wa, 0);
        ISSUE8(wa, a1);
        WAITV(8);  MF8(1, wb, 8);
        ISSUE8(wb, a1 + 512);
        WAITV(8);  MF8(0, wa, 16);
        ISSUE8(wa, a1 + 16384);
        WAITV(8);  MF8(0, wb, 24);
        ISSUE8(wb, a1 + 16896);
        WAITV(8);  MF8(1, wa, 16);
        WAITV(0);  MF8(1, wb, 24);
      }
      // --- gate nonlinearities (all lanes), then combine in gate==0 lanes ---
      ushort* hw = isL0 ? h0bufs[p & 1] : h1bufs[(p - 1) & 1];
#pragma unroll
      for (int tau = 0; tau < 2; tau++) {
#pragma unroll
        for (int tt = 0; tt < 2; tt++) {
#pragma unroll
          for (int r = 0; r < 4; r++) {
            float val = acc[tau][tt][r];
            float nl = (gate == 2) ? tanhfast(val) : sigmf(val);
            int base2 = (lane & 48) | u;
            float iv = __shfl(nl, base2);
            float fv = __shfl(nl, base2 | 4);
            float gv = __shfl(nl, base2 | 8);
            float ov = __shfl(nl, base2 | 12);
            if (gate == 0) {
              float cn = fv * cst[tau][tt][r] + iv * gv;
              cst[tau][tt][r] = cn;
              float hn = ov * tanhfast(cn);
              int b = tt * 16 + krow * 4 + r;
              sh[b][tau * 4 + u] = f2bf(hn);
            }
          }
        }
      }
      // --- coalesced coherent store: 32 lanes x 16B ---
      asm volatile("s_waitcnt lgkmcnt(0)" ::: "memory");
      __builtin_amdgcn_sched_barrier(0);
      if (lane < 32) {
        short8 v = *reinterpret_cast<const short8*>(&sh[lane][0]);
        unsigned long long sa = (unsigned long long)hw + stoff;
        asm volatile("global_store_dwordx4 %0, %1, off sc0 sc1"
                     :: "v"(sa), "v"(v) : "memory");
      }
    }
    // ---- grid barrier: monotonic counters, relaxed atomics only ----
    if (p != P - 1) {
      asm volatile("s_waitcnt vmcnt(0)" ::: "memory");  // drain h stores to L3
      if (lane == 0) {
        const int target = p + 1;
        int prev = __hip_atomic_fetch_add(gcnt, 1, __ATOMIC_RELAXED, __HIP_MEMORY_SCOPE_AGENT);
        if (prev == 16 * target - 1) {
          int p2 = __hip_atomic_fetch_add(root, 1, __ATOMIC_RELAXED, __HIP_MEMORY_SCOPE_AGENT);
          if (p2 == 8 * target - 1) {
            __hip_atomic_store(gen, target, __ATOMIC_RELAXED, __HIP_MEMORY_SCOPE_AGENT);
          } else {
            while (__hip_atomic_load(gen, __ATOMIC_RELAXED, __HIP_MEMORY_SCOPE_AGENT) < target)
              __builtin_amdgcn_s_sleep(1);
          }
        } else {
          while (__hip_atomic_load(gen, __ATOMIC_RELAXED, __HIP_MEMORY_SCOPE_AGENT) < target)
            __builtin_amdgcn_s_sleep(1);
        }
      }
      // no fence: next phase reads h via sc0sc1 (L3-direct), caches never stale
    }
  }
}

// ---------------- FC + log_softmax ----------------
__global__ __launch_bounds__(256) void k_fc(const ushort* __restrict__ h1,
                                            const float* __restrict__ fcw,
                                            const float* __restrict__ fcb,
                                            float* __restrict__ out) {
  __shared__ float hsh[HH];
  __shared__ float red[256];
  const int b = blockIdx.x, tid = threadIdx.x;
  for (int k = tid; k < HH; k += 256) hsh[k] = bf2f(h1[b * HH + k]);
  __syncthreads();
  float lg[4];
#pragma unroll
  for (int q = 0; q < 4; q++) {
    int o = q * 256 + tid;
    float acc = fcb[o];
    const float* wr = fcw + (size_t)o * HH;
#pragma unroll 4
    for (int k = 0; k < HH; k += 4) {
      float4 w4 = *reinterpret_cast<const float4*>(wr + k);
      acc += hsh[k] * w4.x + hsh[k + 1] * w4.y + hsh[k + 2] * w4.z + hsh[k + 3] * w4.w;
    }
    lg[q] = acc;
  }
  float m = fmaxf(fmaxf(lg[0], lg[1]), fmaxf(lg[2], lg[3]));
  red[tid] = m; __syncthreads();
  for (int s = 128; s > 0; s >>= 1) { if (tid < s) red[tid] = fmaxf(red[tid], red[tid + s]); __syncthreads(); }
  m = red[0]; __syncthreads();
  float se = 0.f;
#pragma unroll
  for (int q = 0; q < 4; q++) se += __expf(lg[q] - m);
  red[tid] = se; __syncthreads();
  for (int s = 128; s > 0; s >>= 1) { if (tid < s) red[tid] += red[tid + s]; __syncthreads(); }
  float lse = m + logf(red[0]);
#pragma unroll
  for (int q = 0; q < 4; q++) out[b * OO + q * 256 + tid] = lg[q] - lse;
}

extern "C" void kernel_launch(void* const* d_in, const int* in_sizes, int n_in,
                              void* d_out, int out_size, void* d_ws, size_t ws_size,
                              hipStream_t stream) {
  const float* x     = (const float*)d_in[0];
  const float* h0    = (const float*)d_in[1];
  const float* c0    = (const float*)d_in[2];
  const float* w_ih0 = (const float*)d_in[3];
  const float* w_hh0 = (const float*)d_in[4];
  const float* b_ih0 = (const float*)d_in[5];
  const float* b_hh0 = (const float*)d_in[6];
  const float* w_ih1 = (const float*)d_in[7];
  const float* w_hh1 = (const float*)d_in[8];
  const float* b_ih1 = (const float*)d_in[9];
  const float* b_hh1 = (const float*)d_in[10];
  const float* fcw   = (const float*)d_in[11];
  const float* fcb   = (const float*)d_in[12];
  float* out = (float*)d_out;

  char* ws = (char*)d_ws;
  size_t off = 0;
  ushort* xb = (ushort*)(ws + off); off += (size_t)TT * BB * II * 2;
  ushort* h0b0 = (ushort*)(ws + off); off += BB * HH * 2;
  ushort* h0b1 = (ushort*)(ws + off); off += BB * HH * 2;
  ushort* h1b0 = (ushort*)(ws + off); off += BB * HH * 2;
  ushort* h1b1 = (ushort*)(ws + off); off += BB * HH * 2;
  int* bar = (int*)(ws + off); off += 1024 * sizeof(int);

  k_convert_x<<<2048, 256, 0, stream>>>(x, xb, TT * BB * II / 4);
  k_init<<<1, 256, 0, stream>>>(h0, h0b1, h1b1, bar);
  k_lstm<<<NWG, 64, 0, stream>>>(xb, w_ih0, w_hh0, b_ih0, b_hh0,
                                 w_ih1, w_hh1, b_ih1, b_hh1, c0,
                                 h0b0, h0b1, h1b0, h1b1, bar);
  k_fc<<<BB, 256, 0, stream>>>(h1b1, fcw, fcb, out);
}

// Round 5
// 16115.796 us; speedup vs baseline: 4.3490x; 1.0937x over previous
//
#include <hip/hip_runtime.h>
#include <stdint.h>

// Problem dims
#define TT 2048
#define BB 32
#define II 256
#define HH 512
#define OO 1024
#define NWGL 64    // WGs per layer (each owns 8 hidden units = 32 gate columns)
#define NWG 128
#define RING 32    // h0 ring slots (32 KB each)

typedef __attribute__((ext_vector_type(8))) short short8;
typedef __attribute__((ext_vector_type(4))) float floatx4;

__device__ __forceinline__ unsigned short f2bf(float f) {
  union { float f; unsigned u; } v; v.f = f;
  unsigned r = v.u + 0x7FFFu + ((v.u >> 16) & 1u);  // RNE
  return (unsigned short)(r >> 16);
}
__device__ __forceinline__ float bf2f(unsigned short b) {
  union { float f; unsigned u; } v; v.u = ((unsigned)b) << 16; return v.f;
}
__device__ __forceinline__ float sigmf(float x) { return 1.0f / (1.0f + __expf(-x)); }
__device__ __forceinline__ float tanhfast(float x) {
  float xc = fminf(fmaxf(x, -15.f), 15.f);
  float e = __expf(2.f * xc);
  return (e - 1.f) / (e + 1.f);
}

// Coherent (L3-direct) 16B load via 64-bit VGPR address: d <- [va + IMM].
#define LD1(d, va, IMM)                                                     \
  asm volatile("global_load_dwordx4 %0, %1, off offset:" IMM " sc0 sc1"     \
               : "=v"(d) : "v"(va) : "memory")
// Cached 16B load (normal L1/L2 path) — for read-only x.
#define LD1C(d, va, IMM)                                                    \
  asm volatile("global_load_dwordx4 %0, %1, off offset:" IMM                \
               : "=v"(d) : "v"(va) : "memory")

#define ISSUE8(dst, va) do {                                                \
    LD1(dst[0], va, "0");   LD1(dst[1], va, "64");                          \
    LD1(dst[2], va, "128"); LD1(dst[3], va, "192");                         \
    LD1(dst[4], va, "256"); LD1(dst[5], va, "320");                         \
    LD1(dst[6], va, "384"); LD1(dst[7], va, "448"); } while (0)
#define ISSUE8C(dst, va) do {                                               \
    LD1C(dst[0], va, "0");   LD1C(dst[1], va, "64");                        \
    LD1C(dst[2], va, "128"); LD1C(dst[3], va, "192");                       \
    LD1C(dst[4], va, "256"); LD1C(dst[5], va, "320");                       \
    LD1C(dst[6], va, "384"); LD1C(dst[7], va, "448"); } while (0)

// Wait until <=N vector-mem ops outstanding; fence the scheduler (rule #18).
#define WAITV(N) do {                                                       \
    asm volatile("s_waitcnt vmcnt(" #N ")" ::: "memory");                   \
    __builtin_amdgcn_sched_barrier(0); } while (0)

#define MF8(tt_, src, wbase) do {                                           \
    _Pragma("unroll")                                                       \
    for (int j = 0; j < 8; j++) {                                           \
      acc[0][tt_] = __builtin_amdgcn_mfma_f32_16x16x32_bf16(src[j], wf[0][(wbase) + j], acc[0][tt_], 0, 0, 0); \
      acc[1][tt_] = __builtin_amdgcn_mfma_f32_16x16x32_bf16(src[j], wf[1][(wbase) + j], acc[1][tt_], 0, 0, 0); \
    } } while (0)

// Relaxed agent-scope read of a progress counter via asm (uncounted by the
// compiler's waitcnt pass; collected by our own WAITV(0)).
#define PROGREAD(dst, addr64)                                               \
  asm volatile("global_load_dword %0, %1, off sc0 sc1"                      \
               : "=v"(dst) : "v"(addr64) : "memory")

// Two-level (8 groups x 8) monotonic barrier among 64 waves.
#define BARRIER(gcnt, root, gen, target, do_poll) do {                      \
  if (lane == 0) {                                                          \
    int prev = __hip_atomic_fetch_add(gcnt, 1, __ATOMIC_RELAXED, __HIP_MEMORY_SCOPE_AGENT); \
    if (prev == 8 * (target) - 1) {                                         \
      int p2 = __hip_atomic_fetch_add(root, 1, __ATOMIC_RELAXED, __HIP_MEMORY_SCOPE_AGENT); \
      if (p2 == 8 * (target) - 1) {                                         \
        __hip_atomic_store(gen, (target), __ATOMIC_RELAXED, __HIP_MEMORY_SCOPE_AGENT); \
      } else if (do_poll) {                                                 \
        while (__hip_atomic_load(gen, __ATOMIC_RELAXED, __HIP_MEMORY_SCOPE_AGENT) < (target)) \
          __builtin_amdgcn_s_sleep(1);                                      \
      }                                                                     \
    } else if (do_poll) {                                                   \
      while (__hip_atomic_load(gen, __ATOMIC_RELAXED, __HIP_MEMORY_SCOPE_AGENT) < (target)) \
        __builtin_amdgcn_s_sleep(1);                                        \
    }                                                                       \
  } } while (0)

// Gate nonlinearities + c/h update + LDS pack + coalesced coherent h store.
#define TAIL(hwaddr) do {                                                   \
  _Pragma("unroll")                                                         \
  for (int tau = 0; tau < 2; tau++) {                                       \
    _Pragma("unroll")                                                       \
    for (int tt = 0; tt < 2; tt++) {                                        \
      _Pragma("unroll")                                                     \
      for (int r = 0; r < 4; r++) {                                         \
        float val = acc[tau][tt][r];                                        \
        float nl = (gate == 2) ? tanhfast(val) : sigmf(val);                \
        int base2 = (lane & 48) | u;                                        \
        float iv = __shfl(nl, base2);                                       \
        float fv = __shfl(nl, base2 | 4);                                   \
        float gv = __shfl(nl, base2 | 8);                                   \
        float ov = __shfl(nl, base2 | 12);                                  \
        if (gate == 0) {                                                    \
          float cn = fv * cst[tau][tt][r] + iv * gv;                        \
          cst[tau][tt][r] = cn;                                             \
          float hn = ov * tanhfast(cn);                                     \
          int b = tt * 16 + krow * 4 + r;                                   \
          sh[b][tau * 4 + u] = f2bf(hn);                                    \
        }                                                                   \
      }                                                                     \
    }                                                                       \
  }                                                                         \
  asm volatile("s_waitcnt lgkmcnt(0)" ::: "memory");                        \
  __builtin_amdgcn_sched_barrier(0);                                        \
  if (lane < 32) {                                                          \
    short8 v = *reinterpret_cast<const short8*>(&sh[lane][0]);              \
    unsigned long long sa = (hwaddr) + stoff;                               \
    asm volatile("global_store_dwordx4 %0, %1, off sc0 sc1"                 \
                 :: "v"(sa), "v"(v) : "memory");                            \
  } } while (0)

// ---------------- x fp32 -> bf16 convert ----------------
__global__ void k_convert_x(const float* __restrict__ x, ushort* __restrict__ xb, int n4) {
  int i = blockIdx.x * blockDim.x + threadIdx.x;
  int stride = gridDim.x * blockDim.x;
  const float4* xf = reinterpret_cast<const float4*>(x);
  ushort4* ob = reinterpret_cast<ushort4*>(xb);
  for (; i < n4; i += stride) {
    float4 f = xf[i];
    ushort4 o;
    o.x = f2bf(f.x); o.y = f2bf(f.y); o.z = f2bf(f.z); o.w = f2bf(f.w);
    ob[i] = o;
  }
}

// ---------------- init: h0 init -> ring slot 31, h1 init -> h1b1, zero bar ----
__global__ void k_init(const float* __restrict__ h0in, ushort* __restrict__ ring,
                       ushort* __restrict__ h1b1, int* __restrict__ bar) {
  int i = threadIdx.x;
  ushort* slot31 = ring + (RING - 1) * BB * HH;
  for (int k = i; k < BB * HH; k += blockDim.x) {
    slot31[k] = f2bf(h0in[k]);
    h1b1[k]   = f2bf(h0in[BB * HH + k]);
  }
  for (int k = i; k < 1024; k += blockDim.x) bar[k] = 0;
}

// ---------------- persistent recurrence kernel ----------------
// 128 WGs x 1 wave, two DECOUPLED layer loops.
// L0 (wg 0..63): phase t computes h0[t] from x[t] (cached) + h0[t-1] (ring,
//   coherent); publishes gen0 = t+1 via its own 64-wave barrier.
// L1 (wg 64..127): phase t computes h1[t] from h0[t] (ring, gated by gen0)
//   + h1[t-1] (ping-pong); own 64-wave barrier (gen1).
// All coherent loads issued up front (32 in flight), counted vmcnt waits ->
// ~one L3 latency per phase. No cache-wide ops anywhere in the loop.
__global__ __launch_bounds__(64, 1) void k_lstm(
    const ushort* __restrict__ xb,
    const float* __restrict__ w_ih0, const float* __restrict__ w_hh0,
    const float* __restrict__ b_ih0, const float* __restrict__ b_hh0,
    const float* __restrict__ w_ih1, const float* __restrict__ w_hh1,
    const float* __restrict__ b_ih1, const float* __restrict__ b_hh1,
    const float* __restrict__ c0in,
    ushort* __restrict__ ring,
    ushort* __restrict__ h1b0, ushort* __restrict__ h1b1,
    int* __restrict__ bar)
{
  __shared__ ushort sh[BB][8];  // 512B store-coalescing tile
  const int wg = blockIdx.x;
  const int lane = threadIdx.x;
  const bool isL0 = wg < NWGL;
  const int g = isL0 ? wg : wg - NWGL;
  const int col = lane & 15;
  const int krow = lane >> 4;
  const int u = col & 3;
  const int gate = col >> 2;  // 0=i 1=f 2=g 3=o

  // --- pack weight B-fragments into registers (bf16) ---
  short8 wf[2][32];
#define LOADW(dst, base, rowlen, kbase, tau) do {                             \
    const int _grow = gate * HH + g * 8 + (tau) * 4 + u;                      \
    const float* _p = (base) + (size_t)_grow * (rowlen) + (kbase) + krow * 8; \
    short8 _r;                                                                \
    _Pragma("unroll")                                                         \
    for (int _j = 0; _j < 8; _j++) _r[_j] = (short)f2bf(_p[_j]);              \
    (dst) = _r; } while (0)

  if (isL0) {
#pragma unroll
    for (int tau = 0; tau < 2; tau++) {
#pragma unroll
      for (int kk = 0; kk < 8; kk++)  LOADW(wf[tau][kk],      w_ih0, II, kk * 32, tau);
#pragma unroll
      for (int kk = 0; kk < 16; kk++) LOADW(wf[tau][8 + kk],  w_hh0, HH, kk * 32, tau);
    }
  } else {
#pragma unroll
    for (int tau = 0; tau < 2; tau++) {
#pragma unroll
      for (int kk = 0; kk < 16; kk++) LOADW(wf[tau][kk],      w_ih1, HH, kk * 32, tau);
#pragma unroll
      for (int kk = 0; kk < 16; kk++) LOADW(wf[tau][16 + kk], w_hh1, HH, kk * 32, tau);
    }
  }
  float bias[2];
#pragma unroll
  for (int tau = 0; tau < 2; tau++) {
    const int grow = gate * HH + g * 8 + tau * 4 + u;
    bias[tau] = isL0 ? (b_ih0[grow] + b_hh0[grow]) : (b_ih1[grow] + b_hh1[grow]);
  }

  // --- c state in fp32 registers (used in gate==0 lanes) ---
  float cst[2][2][4];
  {
    const float* cbase = c0in + (isL0 ? 0 : 1) * BB * HH;
#pragma unroll
    for (int tau = 0; tau < 2; tau++)
#pragma unroll
      for (int tt = 0; tt < 2; tt++)
#pragma unroll
        for (int r = 0; r < 4; r++) {
          int b = tt * 16 + krow * 4 + r;
          cst[tau][tt][r] = cbase[b * HH + g * 8 + tau * 4 + u];
        }
  }

  // barrier/counter layout in bar[1024]
  int* gcnt = bar + (isL0 ? 0 : 320) + (g >> 3) * 32;
  int* root = bar + (isL0 ? 256 : 576);
  int* gen  = bar + (isL0 ? 288 : 608);
  const unsigned long long genOther =
      (unsigned long long)(bar + (isL0 ? 608 : 288));

  // per-lane byte offsets
  const int vo00 = col * 1024 + krow * 16;   // [32][512]bf16 tile, tt=0
  const unsigned long long stoff = (unsigned long long)(lane * 1024 + g * 16);
  ushort* h1bufs[2] = { h1b0, h1b1 };

  short8 wa[8], wb[8], wc[8], wd[8];
  floatx4 acc[2][2];
  const floatx4 bi0 = (floatx4){ bias[0], bias[0], bias[0], bias[0] };
  const floatx4 bi1 = (floatx4){ bias[1], bias[1], bias[1], bias[1] };

  if (isL0) {
    // =============== layer 0 loop ===============
    const unsigned long long xbase = (unsigned long long)xb + (col * 512 + krow * 16);
    int seen1 = 0;
    for (int t = 0; t < TT; ++t) {
      // ring anti-overrun guard vs L1 progress (every 8 phases; slack 24)
      if (((t & 7) == 0) && t >= 32) {
        while (seen1 < t - 24) {
          int sv; PROGREAD(sv, genOther); WAITV(0); seen1 = sv;
          if (seen1 < t - 24) __builtin_amdgcn_s_sleep(8);
        }
      }
      acc[0][0] = bi0; acc[0][1] = bi0; acc[1][0] = bi1; acc[1][1] = bi1;
      const unsigned long long ha =
          (unsigned long long)ring + ((t + RING - 1) & (RING - 1)) * (BB * HH * 2) + vo00;
      const unsigned long long xa = xbase + (unsigned long long)t * (BB * II * 2);
      ISSUE8(wa, ha); ISSUE8(wb, ha + 512); ISSUE8(wc, ha + 16384); ISSUE8(wd, ha + 16896);
      WAITV(24); MF8(0, wa, 8);  ISSUE8C(wa, xa);
      WAITV(24); MF8(0, wb, 16); ISSUE8C(wb, xa + 8192);
      WAITV(24); MF8(1, wc, 8);
      WAITV(16); MF8(1, wd, 16);
      WAITV(8);  MF8(0, wa, 0);
      WAITV(0);  MF8(1, wb, 0);
      const unsigned long long hw =
          (unsigned long long)ring + (t & (RING - 1)) * (BB * HH * 2);
      TAIL(hw);
      WAITV(0);  // drain h store
      BARRIER(gcnt, root, gen, t + 1, (t != TT - 1));
    }
  } else {
    // =============== layer 1 loop ===============
    int seen0 = 0;
    int sv_next = 0;
    for (int t = 0; t < TT; ++t) {
      acc[0][0] = bi0; acc[0][1] = bi0; acc[1][0] = bi1; acc[1][1] = bi1;
      const unsigned long long h1a =
          (unsigned long long)h1bufs[(t + 1) & 1] + vo00;
      ISSUE8(wa, h1a); ISSUE8(wb, h1a + 512); ISSUE8(wc, h1a + 16384); ISSUE8(wd, h1a + 16896);
      // gate on L0 progress: need gen0 >= t+1 BEFORE issuing h0[t] reads.
      // seen0 is from a load that completed in an earlier phase (usually passes).
      if (seen0 < t + 1) {
        while (true) {
          int sv; PROGREAD(sv, genOther); WAITV(0); seen0 = sv;
          if (seen0 >= t + 1) break;
          __builtin_amdgcn_s_sleep(8);
        }
      }
      const unsigned long long h0a =
          (unsigned long long)ring + (t & (RING - 1)) * (BB * HH * 2) + vo00;
      WAITV(24); MF8(0, wa, 16); ISSUE8(wa, h0a);
      WAITV(24); MF8(0, wb, 24); ISSUE8(wb, h0a + 512);
      WAITV(24); MF8(1, wc, 16); ISSUE8(wc, h0a + 16384);
      WAITV(24); MF8(1, wd, 24); ISSUE8(wd, h0a + 16896);
      WAITV(24); MF8(0, wa, 0);
      WAITV(16); MF8(0, wb, 8);
      WAITV(8);  MF8(1, wc, 0);
      WAITV(0);  MF8(1, wd, 8);
      const unsigned long long hw = (unsigned long long)h1bufs[t & 1];
      TAIL(hw);
      // overlapped refresh of gen0 (collected by the WAITV(0) below; used next phase)
      PROGREAD(sv_next, genOther);
      WAITV(0);  // drain h store + refresh load
      seen0 = (sv_next > seen0) ? sv_next : seen0;
      if (t != TT - 1) BARRIER(gcnt, root, gen, t + 1, true);
    }
  }
}

// ---------------- FC + log_softmax ----------------
__global__ __launch_bounds__(256) void k_fc(const ushort* __restrict__ h1,
                                            const float* __restrict__ fcw,
                                            const float* __restrict__ fcb,
                                            float* __restrict__ out) {
  __shared__ float hsh[HH];
  __shared__ float red[256];
  const int b = blockIdx.x, tid = threadIdx.x;
  for (int k = tid; k < HH; k += 256) hsh[k] = bf2f(h1[b * HH + k]);
  __syncthreads();
  float lg[4];
#pragma unroll
  for (int q = 0; q < 4; q++) {
    int o = q * 256 + tid;
    float acc = fcb[o];
    const float* wr = fcw + (size_t)o * HH;
#pragma unroll 4
    for (int k = 0; k < HH; k += 4) {
      float4 w4 = *reinterpret_cast<const float4*>(wr + k);
      acc += hsh[k] * w4.x + hsh[k + 1] * w4.y + hsh[k + 2] * w4.z + hsh[k + 3] * w4.w;
    }
    lg[q] = acc;
  }
  float m = fmaxf(fmaxf(lg[0], lg[1]), fmaxf(lg[2], lg[3]));
  red[tid] = m; __syncthreads();
  for (int s = 128; s > 0; s >>= 1) { if (tid < s) red[tid] = fmaxf(red[tid], red[tid + s]); __syncthreads(); }
  m = red[0]; __syncthreads();
  float se = 0.f;
#pragma unroll
  for (int q = 0; q < 4; q++) se += __expf(lg[q] - m);
  red[tid] = se; __syncthreads();
  for (int s = 128; s > 0; s >>= 1) { if (tid < s) red[tid] += red[tid + s]; __syncthreads(); }
  float lse = m + logf(red[0]);
#pragma unroll
  for (int q = 0; q < 4; q++) out[b * OO + q * 256 + tid] = lg[q] - lse;
}

extern "C" void kernel_launch(void* const* d_in, const int* in_sizes, int n_in,
                              void* d_out, int out_size, void* d_ws, size_t ws_size,
                              hipStream_t stream) {
  const float* x     = (const float*)d_in[0];
  const float* h0    = (const float*)d_in[1];
  const float* c0    = (const float*)d_in[2];
  const float* w_ih0 = (const float*)d_in[3];
  const float* w_hh0 = (const float*)d_in[4];
  const float* b_ih0 = (const float*)d_in[5];
  const float* b_hh0 = (const float*)d_in[6];
  const float* w_ih1 = (const float*)d_in[7];
  const float* w_hh1 = (const float*)d_in[8];
  const float* b_ih1 = (const float*)d_in[9];
  const float* b_hh1 = (const float*)d_in[10];
  const float* fcw   = (const float*)d_in[11];
  const float* fcb   = (const float*)d_in[12];
  float* out = (float*)d_out;

  char* ws = (char*)d_ws;
  size_t off = 0;
  ushort* xb   = (ushort*)(ws + off); off += (size_t)TT * BB * II * 2;  // 33.5 MB
  ushort* ring = (ushort*)(ws + off); off += (size_t)RING * BB * HH * 2; // 1 MB
  ushort* h1b0 = (ushort*)(ws + off); off += BB * HH * 2;
  ushort* h1b1 = (ushort*)(ws + off); off += BB * HH * 2;
  int* bar = (int*)(ws + off); off += 1024 * sizeof(int);

  k_convert_x<<<2048, 256, 0, stream>>>(x, xb, TT * BB * II / 4);
  k_init<<<1, 256, 0, stream>>>(h0, ring, h1b1, bar);
  k_lstm<<<NWG, 64, 0, stream>>>(xb, w_ih0, w_hh0, b_ih0, b_hh0,
                                 w_ih1, w_hh1, b_ih1, b_hh1, c0,
                                 ring, h1b0, h1b1, bar);
  // h1[2047] lives in h1 buf[2047&1] = h1b1
  k_fc<<<BB, 256, 0, stream>>>(h1b1, fcw, fcb, out);
}